// Round 2
// baseline (1996.697 us; speedup 1.0000x reference)
//
#include <hip/hip_runtime.h>
#include <hip/hip_bf16.h>

#define H 2160
#define W 3840
#define KS 25
#define PADR 12

// ---------------- blur (25x25 depthwise, edge pad 12) + noise ----------------
#define TX 128
#define TY 16
#define RX 8                 // outputs per thread along x
#define LW (TX + 2 * PADR)   // 152 valid floats per LDS row
#define LH (TY + 2 * PADR)   // 40 rows
#define LSTRIDE 156          // padded row stride

__global__ __launch_bounds__(256) void blur_kernel(
    const float* __restrict__ img, const float* __restrict__ noise,
    const float* __restrict__ g, float* __restrict__ out)
{
    __shared__ float tile[LH * LSTRIDE];   // 24,960 B

    const int bx = blockIdx.x, by = blockIdx.y, c = blockIdx.z;
    const int x0 = bx * TX - PADR;
    const int y0 = by * TY - PADR;
    const float* imgc = img + (size_t)c * (H * W);

    // stage input tile with edge-replicate clamp
    for (int idx = threadIdx.x; idx < LH * LW; idx += 256) {
        int ly = idx / LW;
        int lx = idx - ly * LW;
        int gy = min(max(y0 + ly, 0), H - 1);
        int gx = min(max(x0 + lx, 0), W - 1);
        tile[ly * LSTRIDE + lx] = imgc[(size_t)gy * W + gx];
    }
    __syncthreads();

    const int tx = threadIdx.x & 15;   // 16 thread-cols * 8 outputs = 128
    const int ty = threadIdx.x >> 4;   // 16 thread-rows

    float acc[RX];
    #pragma unroll
    for (int i = 0; i < RX; ++i) acc[i] = 0.f;

    for (int ky = 0; ky < KS; ++ky) {
        // 32-float row segment for this thread: 8 aligned float4 LDS reads
        const float* rp = &tile[(ty + ky) * LSTRIDE + tx * RX];
        float r[RX + 2 * PADR];
        #pragma unroll
        for (int j = 0; j < (RX + 2 * PADR) / 4; ++j) {
            float4 v = *(const float4*)(rp + 4 * j);
            r[4 * j + 0] = v.x; r[4 * j + 1] = v.y;
            r[4 * j + 2] = v.z; r[4 * j + 3] = v.w;
        }
        const float* grow = g + ky * KS;   // wave-uniform -> SGPR loads
        #pragma unroll
        for (int kx = 0; kx < KS; ++kx) {
            float gv = grow[kx];
            #pragma unroll
            for (int i = 0; i < RX; ++i)
                acc[i] = fmaf(r[i + kx], gv, acc[i]);
        }
    }

    const int oy  = by * TY + ty;
    const int ox0 = bx * TX + tx * RX;
    const float* np_ = noise + (size_t)oy * W + ox0;
    float4 n0 = *(const float4*)(np_);
    float4 n1 = *(const float4*)(np_ + 4);

    float* op = out + (size_t)c * (H * W) + (size_t)oy * W + ox0;
    float4 o0 = make_float4(acc[0] + n0.x, acc[1] + n0.y, acc[2] + n0.z, acc[3] + n0.w);
    float4 o1 = make_float4(acc[4] + n1.x, acc[5] + n1.y, acc[6] + n1.z, acc[7] + n1.w);
    *(float4*)(op)     = o0;
    *(float4*)(op + 4) = o1;
}

// ---------------- Laplacian mean( lap^2 ), output grid (H+22) x (W+22) ----------------
#define LH2 (H + 2 * PADR - 2)   // 2182
#define LW2 (W + 2 * PADR - 2)   // 3862

__global__ __launch_bounds__(256) void lap_kernel(
    const float* __restrict__ img, double* __restrict__ sum_ws)
{
    const int ox = blockIdx.x * 256 + threadIdx.x;
    const int oy = blockIdx.y;
    const int c  = blockIdx.z;

    float val = 0.f;
    if (ox < LW2) {
        const float* imgc = img + (size_t)c * (H * W);
        int yc = min(max(oy + 1 - PADR, 0), H - 1);
        int yu = min(max(oy     - PADR, 0), H - 1);
        int yd = min(max(oy + 2 - PADR, 0), H - 1);
        int xc = min(max(ox + 1 - PADR, 0), W - 1);
        int xl = min(max(ox     - PADR, 0), W - 1);
        int xr = min(max(ox + 2 - PADR, 0), W - 1);
        float l = 4.f * imgc[(size_t)yc * W + xc]
                - imgc[(size_t)yu * W + xc] - imgc[(size_t)yd * W + xc]
                - imgc[(size_t)yc * W + xl] - imgc[(size_t)yc * W + xr];
        val = l * l;
    }

    // 64-lane wave reduce
    #pragma unroll
    for (int off = 32; off > 0; off >>= 1)
        val += __shfl_down(val, off, 64);

    __shared__ float wsum[4];
    const int lane = threadIdx.x & 63;
    const int wid  = threadIdx.x >> 6;
    if (lane == 0) wsum[wid] = val;
    __syncthreads();
    if (threadIdx.x == 0) {
        float t = wsum[0] + wsum[1] + wsum[2] + wsum[3];
        atomicAdd(sum_ws, (double)t);
    }
}

__global__ void finalize_kernel(const double* __restrict__ sum_ws,
                                float* __restrict__ out)
{
    double mean = sum_ws[0] / (3.0 * (double)LH2 * (double)LW2);
    out[(size_t)3 * H * W] = (float)mean;
}

extern "C" void kernel_launch(void* const* d_in, const int* in_sizes, int n_in,
                              void* d_out, int out_size, void* d_ws, size_t ws_size,
                              hipStream_t stream)
{
    const float* img   = (const float*)d_in[0];
    const float* noise = (const float*)d_in[1];
    const float* g     = (const float*)d_in[2];
    float* out = (float*)d_out;

    hipMemsetAsync(d_ws, 0, 16, stream);

    blur_kernel<<<dim3(W / TX, H / TY, 3), 256, 0, stream>>>(img, noise, g, out);
    lap_kernel<<<dim3((LW2 + 255) / 256, LH2, 3), 256, 0, stream>>>(
        img, (double*)d_ws);
    finalize_kernel<<<1, 1, 0, stream>>>((const double*)d_ws, out);
}

// Round 3
// 521.987 us; speedup vs baseline: 3.8252x; 3.8252x over previous
//
#include <hip/hip_runtime.h>

#define H 2160
#define W 3840
#define KS 25
#define PADR 12

// ---------------- blur (25x25 depthwise, edge pad 12) + noise ----------------
// 256 threads = 16 tx * 16 ty; each thread computes RX=8 x RY=4 outputs.
// Output tile 128 x 64; LDS input tile 152 x 88 floats = 53,504 B -> 3 blocks/CU.
#define BTX 128
#define BTY 64
#define RX 8
#define RY 4
#define LW (BTX + 2 * PADR)   // 152 (16B-aligned rows: 152*4 = 608 B)
#define LH (BTY + 2 * PADR)   // 88
#define LSTRIDE LW
#define NQX (LW / 4)          // 38 float4 quads per row

__global__ __launch_bounds__(256) void blur_kernel(
    const float* __restrict__ img, const float* __restrict__ noise,
    const float* __restrict__ g, float* __restrict__ out)
{
    __shared__ float tile[LH * LSTRIDE];

    const int bx = blockIdx.x, by = blockIdx.y, c = blockIdx.z;
    const int x0 = bx * BTX - PADR;   // multiple of 4 -> float4-aligned global reads
    const int y0 = by * BTY - PADR;
    const float* imgc = img + (size_t)c * (H * W);

    // stage 152x88 input tile, edge-replicate clamp, float4 fast path
    for (int q = threadIdx.x; q < LH * NQX; q += 256) {
        int ly = q / NQX;
        int qx = q - ly * NQX;
        int lx = qx * 4;
        int gy = min(max(y0 + ly, 0), H - 1);
        const float* row = imgc + (size_t)gy * W;
        int gx0 = x0 + lx;
        float4 v;
        if (gx0 >= 0 && gx0 + 3 <= W - 1) {
            v = *(const float4*)(row + gx0);
        } else {
            v.x = row[min(max(gx0 + 0, 0), W - 1)];
            v.y = row[min(max(gx0 + 1, 0), W - 1)];
            v.z = row[min(max(gx0 + 2, 0), W - 1)];
            v.w = row[min(max(gx0 + 3, 0), W - 1)];
        }
        *(float4*)(&tile[ly * LSTRIDE + lx]) = v;
    }
    __syncthreads();

    const int tx = threadIdx.x & 15;
    const int ty = threadIdx.x >> 4;
    const int xoff = tx * RX;

    float acc[RY][RX];
    #pragma unroll
    for (int yr = 0; yr < RY; ++yr)
        #pragma unroll
        for (int i = 0; i < RX; ++i) acc[yr][i] = 0.f;

    // iterate 28 input rows; each loaded row feeds up to 4 output rows
    for (int t = 0; t < KS + RY - 1; ++t) {
        const float* rp = &tile[(ty * RY + t) * LSTRIDE + xoff];
        float r[RX + KS - 1];   // 32-float sliding window
        #pragma unroll
        for (int j = 0; j < (RX + KS - 1) / 4; ++j) {
            float4 v = *(const float4*)(rp + 4 * j);
            r[4 * j + 0] = v.x; r[4 * j + 1] = v.y;
            r[4 * j + 2] = v.z; r[4 * j + 3] = v.w;
        }
        #pragma unroll
        for (int yr = 0; yr < RY; ++yr) {
            int ky = t - yr;
            if (ky >= 0 && ky < KS) {           // wave-uniform branch
                const float* grow = g + ky * KS; // uniform -> scalar loads
                #pragma unroll
                for (int kx = 0; kx < KS; ++kx) {
                    float gv = grow[kx];
                    #pragma unroll
                    for (int i = 0; i < RX; ++i)
                        acc[yr][i] = fmaf(r[i + kx], gv, acc[yr][i]);
                }
            }
        }
    }

    const int oxbase = bx * BTX + xoff;
    #pragma unroll
    for (int yr = 0; yr < RY; ++yr) {
        int oy = by * BTY + ty * RY + yr;
        if (oy < H) {   // last block row (by=33) is partial
            const float* np_ = noise + (size_t)oy * W + oxbase;
            float4 n0 = *(const float4*)(np_);
            float4 n1 = *(const float4*)(np_ + 4);
            float* op = out + (size_t)c * (H * W) + (size_t)oy * W + oxbase;
            *(float4*)(op) = make_float4(acc[yr][0] + n0.x, acc[yr][1] + n0.y,
                                         acc[yr][2] + n0.z, acc[yr][3] + n0.w);
            *(float4*)(op + 4) = make_float4(acc[yr][4] + n1.x, acc[yr][5] + n1.y,
                                             acc[yr][6] + n1.z, acc[yr][7] + n1.w);
        }
    }
}

// ---------------- Laplacian mean(lap^2), output grid (H+22) x (W+22) ----------------
#define LH2 (H + 2 * PADR - 2)   // 2182
#define LW2 (W + 2 * PADR - 2)   // 3862
#define LAP_TOTAL (3u * LH2 * LW2)
#define LAP_BLOCKS 2048

__global__ __launch_bounds__(256) void lap_kernel(
    const float* __restrict__ img, double* __restrict__ partial)
{
    const unsigned tid = blockIdx.x * 256 + threadIdx.x;
    const unsigned T = LAP_BLOCKS * 256;

    float fsum = 0.f;
    for (unsigned p = tid; p < LAP_TOTAL; p += T) {
        unsigned c   = p / (unsigned)(LH2 * LW2);
        unsigned rem = p - c * (unsigned)(LH2 * LW2);
        unsigned oy  = rem / (unsigned)LW2;
        unsigned ox  = rem - oy * (unsigned)LW2;
        const float* imgc = img + (size_t)c * (H * W);
        int yc = min(max((int)oy + 1 - PADR, 0), H - 1);
        int yu = min(max((int)oy     - PADR, 0), H - 1);
        int yd = min(max((int)oy + 2 - PADR, 0), H - 1);
        int xc = min(max((int)ox + 1 - PADR, 0), W - 1);
        int xl = min(max((int)ox     - PADR, 0), W - 1);
        int xr = min(max((int)ox + 2 - PADR, 0), W - 1);
        float l = 4.f * imgc[(size_t)yc * W + xc]
                - imgc[(size_t)yu * W + xc] - imgc[(size_t)yd * W + xc]
                - imgc[(size_t)yc * W + xl] - imgc[(size_t)yc * W + xr];
        fsum = fmaf(l, l, fsum);
    }

    double v = (double)fsum;
    #pragma unroll
    for (int off = 32; off > 0; off >>= 1)
        v += __shfl_down(v, off, 64);

    __shared__ double wsum[4];
    const int lane = threadIdx.x & 63;
    const int wid  = threadIdx.x >> 6;
    if (lane == 0) wsum[wid] = v;
    __syncthreads();
    if (threadIdx.x == 0)
        partial[blockIdx.x] = wsum[0] + wsum[1] + wsum[2] + wsum[3];
}

__global__ __launch_bounds__(256) void finalize_kernel(
    const double* __restrict__ partial, float* __restrict__ out)
{
    double v = 0.0;
    for (int i = threadIdx.x; i < LAP_BLOCKS; i += 256) v += partial[i];
    #pragma unroll
    for (int off = 32; off > 0; off >>= 1)
        v += __shfl_down(v, off, 64);

    __shared__ double wsum[4];
    const int lane = threadIdx.x & 63;
    const int wid  = threadIdx.x >> 6;
    if (lane == 0) wsum[wid] = v;
    __syncthreads();
    if (threadIdx.x == 0) {
        double mean = (wsum[0] + wsum[1] + wsum[2] + wsum[3])
                    / (3.0 * (double)LH2 * (double)LW2);
        out[(size_t)3 * H * W] = (float)mean;
    }
}

extern "C" void kernel_launch(void* const* d_in, const int* in_sizes, int n_in,
                              void* d_out, int out_size, void* d_ws, size_t ws_size,
                              hipStream_t stream)
{
    const float* img   = (const float*)d_in[0];
    const float* noise = (const float*)d_in[1];
    const float* g     = (const float*)d_in[2];
    float* out = (float*)d_out;
    double* partial = (double*)d_ws;   // 2048 doubles = 16 KB; every slot written each call

    blur_kernel<<<dim3(W / BTX, (H + BTY - 1) / BTY, 3), 256, 0, stream>>>(
        img, noise, g, out);
    lap_kernel<<<dim3(LAP_BLOCKS), 256, 0, stream>>>(img, partial);
    finalize_kernel<<<1, 256, 0, stream>>>(partial, out);
}